// Round 3
// baseline (1406.107 us; speedup 1.0000x reference)
//
#include <hip/hip_runtime.h>
#include <hip/hip_bf16.h>

#define NN 200000
#define NE 400000
#define NG 8000
#define HID 128
#define OUTD 256
#define NODE_TOT 178
#define EDGE_TOT 30

typedef __attribute__((ext_vector_type(8))) short bfrag8;
typedef __attribute__((ext_vector_type(4))) float f32x4;
typedef unsigned short ushort_t;

__constant__ int c_noff[10] = {0,119,128,139,151,161,166,174,176,178};
__constant__ int c_eoff[4]  = {0,22,28,30};

__device__ __forceinline__ ushort_t f2bf(float f) {
  union { float f; unsigned u; } x; x.f = f;
  unsigned r = x.u + 0x7fffu + ((x.u >> 16) & 1u);
  return (ushort_t)(r >> 16);
}
__device__ __forceinline__ float bf2f(ushort_t u) {
  union { unsigned u; float f; } x; x.u = ((unsigned)u) << 16;
  return x.f;
}

// Projected embedding tables: PN[r][d] = emb[r] . W_c[:,d] (+bias folded into col 0)
__global__ __launch_bounds__(128) void build_tables(
    const float* __restrict__ node_emb, const float* __restrict__ edge_emb,
    const float* __restrict__ npw, const float* __restrict__ npb,
    const float* __restrict__ epw, const float* __restrict__ epb,
    float* __restrict__ PN, float* __restrict__ PE)
{
  int r = blockIdx.x, d = threadIdx.x;
  if (r < NODE_TOT) {
    int c = 0;
    while (r >= c_noff[c+1]) c++;
    float acc = (c == 0) ? npb[d] : 0.f;
    const float* er = node_emb + r*HID;
    const float* wb = npw + (size_t)(c*HID)*HID + d;
    for (int k = 0; k < HID; k++) acc += er[k] * wb[(size_t)k*HID];
    PN[r*HID + d] = acc;
  } else {
    int re = r - NODE_TOT;
    int c = 0;
    while (re >= c_eoff[c+1]) c++;
    float acc = (c == 0) ? epb[d] : 0.f;
    const float* er = edge_emb + re*HID;
    const float* wb = epw + (size_t)(c*HID)*HID + d;
    for (int k = 0; k < HID; k++) acc += er[k] * wb[(size_t)k*HID];
    PE[re*HID + d] = acc;
  }
}

// Pack mlp_w1/mlp_w2 into bf16 MFMA B-fragment order:
// packed[(((layer*2+isw2)*32 + nt*4+kt)*64 + lane)*8 + j] = W[k][n],
//   n = nt*16 + (lane&15), k = kt*32 + (lane>>4)*8 + j
__global__ __launch_bounds__(256) void pack_w(const float* __restrict__ w1,
                                              const float* __restrict__ w2,
                                              ushort_t* __restrict__ pw)
{
  int t = blockIdx.x*256 + threadIdx.x;     // 12288 total
  int lane = t & 63, tile = (t >> 6) & 31, pair = t >> 11;
  int layer = pair >> 1, isw2 = pair & 1;
  int nt = tile >> 2, kt = tile & 3;
  int n  = nt*16 + (lane & 15);
  int k0 = kt*32 + ((lane >> 4) << 3);
  const float* src = (isw2 ? w2 : w1) + (size_t)layer*HID*HID;
  ushort_t* dst = pw + (size_t)t*8;
  #pragma unroll
  for (int j = 0; j < 8; j++) dst[j] = f2bf(src[(size_t)(k0+j)*HID + n]);
}

__global__ __launch_bounds__(256) void node_embed(const int* __restrict__ x,
                                                  const float* __restrict__ PN,
                                                  ushort_t* __restrict__ h)
{
  int gid = blockIdx.x*256 + threadIdx.x;   // 200000*128 exact
  int i = gid >> 7, d = gid & 127;
  const int* xr = x + i*9;
  float acc = 0.f;
  #pragma unroll
  for (int c = 0; c < 9; c++) acc += PN[(c_noff[c] + xr[c])*HID + d];
  h[gid] = f2bf(acc);
}

// one wave per edge: m = relu(h[src] + PE[a0]+PE[a1]+PE[a2]); atomic scatter to agg[dst]
__global__ __launch_bounds__(256) void edge_msg(const int* __restrict__ ei,
                                                const int* __restrict__ ea,
                                                const float* __restrict__ PE,
                                                const ushort_t* __restrict__ h,
                                                float* __restrict__ agg)
{
  int e = blockIdx.x*4 + (threadIdx.x >> 6);
  int lane = threadIdx.x & 63;
  int src = ei[e], dst = ei[NE + e];
  const int* ar = ea + e*3;
  unsigned hv = ((const unsigned*)h)[(size_t)src*64 + lane];   // 2 bf16
  const float2* p2 = (const float2*)PE;
  float2 t0 = p2[(ar[0])*64 + lane];
  float2 t1 = p2[(22 + ar[1])*64 + lane];
  float2 t2 = p2[(28 + ar[2])*64 + lane];
  float mx = fmaxf(bf2f((ushort_t)(hv & 0xffffu)) + t0.x + t1.x + t2.x, 0.f);
  float my = fmaxf(bf2f((ushort_t)(hv >> 16))    + t0.y + t1.y + t2.y, 0.f);
  float* ap = agg + (size_t)dst*HID + lane*2;
  atomicAdd(ap,   mx);
  atomicAdd(ap+1, my);
}

// Fused GINE MLP, IN-PLACE on bf16 h: z = h+agg; h = relu(relu(z@W1+b1)@W2+b2).
// Block = 4 waves x 16 rows = 64 rows, full 128 cols. Safe in-place: each block
// reads only its own 64 rows (all before the __syncthreads), writes them after.
__global__ __launch_bounds__(256) void mlp_fused(ushort_t* __restrict__ h,
                                                 const float* __restrict__ agg,
                                                 const ushort_t* __restrict__ pw,
                                                 const float* __restrict__ b1,
                                                 const float* __restrict__ b2)
{
  __shared__ ushort_t tT[64*136];           // padded stride 136: 2-way (free) bank aliasing
  int tid = threadIdx.x;
  int w = tid >> 6, lane = tid & 63;
  int rbase = blockIdx.x*64 + w*16;
  int arow = rbase + (lane & 15);
  int acol = (lane >> 4) << 3;

  // A fragments of z = h + agg (h already bf16: single 16B load per fragment)
  bfrag8 afr[4];
  #pragma unroll
  for (int kt = 0; kt < 4; kt++) {
    int c = kt*32 + acol;
    bfrag8 hfr = *(const bfrag8*)(h + (size_t)arow*HID + c);
    const f32x4* gp = (const f32x4*)(agg + (size_t)arow*HID + c);
    f32x4 g0 = gp[0], g1 = gp[1];
    bfrag8 fr;
    #pragma unroll
    for (int j = 0; j < 4; j++) fr[j]   = (short)f2bf(bf2f((ushort_t)hfr[j])   + g0[j]);
    #pragma unroll
    for (int j = 0; j < 4; j++) fr[4+j] = (short)f2bf(bf2f((ushort_t)hfr[4+j]) + g1[j]);
    afr[kt] = fr;
  }

  int ncol = lane & 15;
  const bfrag8* w1 = (const bfrag8*)pw;             // fragment-ordered
  const bfrag8* w2 = (const bfrag8*)(pw + 16384);

  f32x4 acc[8];
  #pragma unroll
  for (int nt = 0; nt < 8; nt++) {
    float b = b1[nt*16 + ncol];
    acc[nt][0]=b; acc[nt][1]=b; acc[nt][2]=b; acc[nt][3]=b;
  }
  #pragma unroll
  for (int kt = 0; kt < 4; kt++)
    #pragma unroll
    for (int nt = 0; nt < 8; nt++)
      acc[nt] = __builtin_amdgcn_mfma_f32_16x16x32_bf16(afr[kt], w1[(nt*4+kt)*64 + lane], acc[nt], 0, 0, 0);

  // t = relu(.) -> LDS (layout change for GEMM2's A operand)
  #pragma unroll
  for (int nt = 0; nt < 8; nt++) {
    int col = nt*16 + ncol;
    #pragma unroll
    for (int r = 0; r < 4; r++) {
      int row = w*16 + ((lane >> 4) << 2) + r;
      tT[row*136 + col] = f2bf(fmaxf(acc[nt][r], 0.f));
    }
  }
  __syncthreads();

  bfrag8 afr2[4];
  int trow = (w*16 + (lane & 15))*136;
  #pragma unroll
  for (int kt = 0; kt < 4; kt++)
    afr2[kt] = *(const bfrag8*)&tT[trow + kt*32 + acol];

  f32x4 acc2[8];
  #pragma unroll
  for (int nt = 0; nt < 8; nt++) {
    float b = b2[nt*16 + ncol];
    acc2[nt][0]=b; acc2[nt][1]=b; acc2[nt][2]=b; acc2[nt][3]=b;
  }
  #pragma unroll
  for (int kt = 0; kt < 4; kt++)
    #pragma unroll
    for (int nt = 0; nt < 8; nt++)
      acc2[nt] = __builtin_amdgcn_mfma_f32_16x16x32_bf16(afr2[kt], w2[(nt*4+kt)*64 + lane], acc2[nt], 0, 0, 0);

  #pragma unroll
  for (int nt = 0; nt < 8; nt++) {
    int col = nt*16 + ncol;
    #pragma unroll
    for (int r = 0; r < 4; r++) {
      int row = rbase + ((lane >> 4) << 2) + r;
      h[(size_t)row*HID + col] = f2bf(fmaxf(acc2[nt][r], 0.f));
    }
  }
}

__device__ __forceinline__ int lowerb(const int* a, int n, int v) {
  int lo = 0, hi = n;
  while (lo < hi) { int m = (lo + hi) >> 1; if (a[m] < v) lo = m + 1; else hi = m; }
  return lo;
}

__global__ __launch_bounds__(128) void pool(const ushort_t* __restrict__ h,
                                            const int* __restrict__ batch,
                                            float* __restrict__ gf)
{
  int g = blockIdx.x, d = threadIdx.x;
  int s = lowerb(batch, NN, g), e = lowerb(batch, NN, g + 1);
  float acc = 0.f;
  for (int i = s; i < e; i++) acc += bf2f(h[(size_t)i*HID + d]);
  gf[g*HID + d] = acc;
}

// p = gf @ proj_w + b; row-normalize. 16 graphs per block.
__global__ __launch_bounds__(256) void final_proj(const float* __restrict__ gf,
                                                  const float* __restrict__ W,
                                                  const float* __restrict__ b,
                                                  float* __restrict__ out)
{
  __shared__ float gls[16*128];
  __shared__ float part[16][4];
  int tid = threadIdx.x;
  int gbase = blockIdx.x*16;
  for (int idx = tid; idx < 2048; idx += 256) gls[idx] = gf[(size_t)gbase*128 + idx];
  __syncthreads();
  float acc[16];
  #pragma unroll
  for (int g = 0; g < 16; g++) acc[g] = 0.f;
  for (int k = 0; k < 128; k++) {
    float wv = W[(size_t)k*256 + tid];
    #pragma unroll
    for (int g = 0; g < 16; g++) acc[g] += gls[g*128 + k] * wv;
  }
  float bj = b[tid];
  int wid = tid >> 6, lane = tid & 63;
  #pragma unroll
  for (int g = 0; g < 16; g++) {
    acc[g] += bj;
    float s = acc[g]*acc[g];
    #pragma unroll
    for (int off = 32; off > 0; off >>= 1) s += __shfl_xor(s, off, 64);
    if (lane == 0) part[g][wid] = s;
  }
  __syncthreads();
  #pragma unroll
  for (int g = 0; g < 16; g++) {
    float S = part[g][0] + part[g][1] + part[g][2] + part[g][3];
    float rn = 1.f / fmaxf(sqrtf(S), 1e-12f);
    out[(size_t)(gbase + g)*256 + tid] = acc[g]*rn;
  }
}

// Fallback when ws_size is insufficient: out[0] encodes ws_size (diagnostic),
// rest zero. No d_ws access at all.
__global__ __launch_bounds__(256) void ws_diag(float* __restrict__ out, int n, float wsval) {
  int i = blockIdx.x*256 + threadIdx.x;
  if (i < n) out[i] = (i == 0) ? wsval : 0.f;
}

extern "C" void kernel_launch(void* const* d_in, const int* in_sizes, int n_in,
                              void* d_out, int out_size, void* d_ws, size_t ws_size,
                              hipStream_t stream)
{
  const int*   x     = (const int*)d_in[0];
  const int*   ea    = (const int*)d_in[1];
  const int*   ei    = (const int*)d_in[2];
  const int*   batch = (const int*)d_in[3];
  const float* nemb  = (const float*)d_in[4];
  const float* eemb  = (const float*)d_in[5];
  const float* npw   = (const float*)d_in[6];
  const float* npb   = (const float*)d_in[7];
  const float* epw   = (const float*)d_in[8];
  const float* epb   = (const float*)d_in[9];
  const float* w1    = (const float*)d_in[10];
  const float* b1    = (const float*)d_in[11];
  const float* w2    = (const float*)d_in[12];
  const float* b2    = (const float*)d_in[13];
  const float* pjw   = (const float*)d_in[14];
  const float* pjb   = (const float*)d_in[15];
  float* out = (float*)d_out;

  char* ws = (char*)d_ws;
  size_t off = 0;
  auto carve = [&](size_t bytes) -> char* {
    char* p = ws + off;
    off = (off + bytes + 255) & ~(size_t)255;
    return p;
  };
  float*    PN  = (float*)carve((size_t)NODE_TOT*HID*4);   //  91 KB
  float*    PE  = (float*)carve((size_t)EDGE_TOT*HID*4);   //  15 KB
  ushort_t* PW  = (ushort_t*)carve((size_t)3*2*HID*HID*2); // 197 KB
  ushort_t* h   = (ushort_t*)carve((size_t)NN*HID*2);      //  51.2 MB (bf16, in-place)
  float*    agg = (float*)carve((size_t)NN*HID*4);         // 102.4 MB
  float*    gf  = (float*)carve((size_t)NG*HID*4);         //   4.1 MB
                                                           // total ~158 MB

  if (off > ws_size) {
    // workspace too small — emit diagnostic (absmax ~= ws_size) instead of faulting
    ws_diag<<<(out_size + 255)/256, 256, 0, stream>>>(out, out_size, (float)ws_size);
    return;
  }

  build_tables<<<NODE_TOT + EDGE_TOT, 128, 0, stream>>>(nemb, eemb, npw, npb, epw, epb, PN, PE);
  pack_w<<<48, 256, 0, stream>>>(w1, w2, PW);
  node_embed<<<(NN*HID)/256, 256, 0, stream>>>(x, PN, h);

  for (int l = 0; l < 3; l++) {
    hipMemsetAsync(agg, 0, (size_t)NN*HID*4, stream);
    edge_msg<<<NE/4, 256, 0, stream>>>(ei, ea, PE, h, agg);
    mlp_fused<<<NN/64, 256, 0, stream>>>(h, agg, PW + (size_t)l*2*HID*HID,
                                         b1 + l*HID, b2 + l*HID);
  }
  pool<<<NG, 128, 0, stream>>>(h, batch, gf);
  final_proj<<<NG/16, 256, 0, stream>>>(gf, pjw, pjb, out);
}

// Round 4
// 555.582 us; speedup vs baseline: 2.5309x; 2.5309x over previous
//
#include <hip/hip_runtime.h>
#include <hip/hip_bf16.h>

#define NN 200000
#define NE 400000
#define NG 8000
#define HID 128
#define OUTD 256
#define NODE_TOT 178
#define EDGE_TOT 30
#define NCOMBO 264          // 22*6*2 distinct edge-attr triples
#define SCAN_NB 196         // ceil(NN/1024)

typedef __attribute__((ext_vector_type(8))) short bfrag8;
typedef __attribute__((ext_vector_type(4))) float f32x4;
typedef unsigned short ushort_t;

__constant__ int c_noff[10] = {0,119,128,139,151,161,166,174,176,178};

__device__ __forceinline__ ushort_t f2bf(float f) {
  union { float f; unsigned u; } x; x.f = f;
  unsigned r = x.u + 0x7fffu + ((x.u >> 16) & 1u);
  return (ushort_t)(r >> 16);
}
__device__ __forceinline__ float bf2f(ushort_t u) {
  union { unsigned u; float f; } x; x.u = ((unsigned)u) << 16;
  return x.f;
}

// Projected embedding tables: PN[r][d] = emb[r] . W_c[:,d] (+bias folded into col 0)
__global__ __launch_bounds__(128) void build_tables(
    const float* __restrict__ node_emb, const float* __restrict__ edge_emb,
    const float* __restrict__ npw, const float* __restrict__ npb,
    const float* __restrict__ epw, const float* __restrict__ epb,
    float* __restrict__ PN, float* __restrict__ PE)
{
  int r = blockIdx.x, d = threadIdx.x;
  if (r < NODE_TOT) {
    int c = 0;
    while (r >= c_noff[c+1]) c++;
    float acc = (c == 0) ? npb[d] : 0.f;
    const float* er = node_emb + r*HID;
    const float* wb = npw + (size_t)(c*HID)*HID + d;
    for (int k = 0; k < HID; k++) acc += er[k] * wb[(size_t)k*HID];
    PN[r*HID + d] = acc;
  } else {
    int re = r - NODE_TOT;
    int c = (re >= 28) ? 2 : (re >= 22 ? 1 : 0);
    float acc = (c == 0) ? epb[d] : 0.f;
    const float* er = edge_emb + re*HID;
    const float* wb = epw + (size_t)(c*HID)*HID + d;
    for (int k = 0; k < HID; k++) acc += er[k] * wb[(size_t)k*HID];
    PE[re*HID + d] = acc;
  }
}

// PE3[(a0*6+a1)*2+a2] = PE[a0] + PE[22+a1] + PE[28+a2]
__global__ __launch_bounds__(128) void build_pe3(const float* __restrict__ PE,
                                                 float* __restrict__ PE3)
{
  int c = blockIdx.x, d = threadIdx.x;
  int a2 = c & 1, a1 = (c >> 1) % 6, a0 = (c >> 1) / 6;
  PE3[c*HID + d] = PE[a0*HID + d] + PE[(22+a1)*HID + d] + PE[(28+a2)*HID + d];
}

// Pack mlp_w1/mlp_w2 into bf16 MFMA B-fragment order
__global__ __launch_bounds__(256) void pack_w(const float* __restrict__ w1,
                                              const float* __restrict__ w2,
                                              ushort_t* __restrict__ pw)
{
  int t = blockIdx.x*256 + threadIdx.x;     // 12288 total
  int lane = t & 63, tile = (t >> 6) & 31, pair = t >> 11;
  int layer = pair >> 1, isw2 = pair & 1;
  int nt = tile >> 2, kt = tile & 3;
  int n  = nt*16 + (lane & 15);
  int k0 = kt*32 + ((lane >> 4) << 3);
  const float* src = (isw2 ? w2 : w1) + (size_t)layer*HID*HID;
  ushort_t* dst = pw + (size_t)t*8;
  #pragma unroll
  for (int j = 0; j < 8; j++) dst[j] = f2bf(src[(size_t)(k0+j)*HID + n]);
}

__global__ __launch_bounds__(256) void node_embed(const int* __restrict__ x,
                                                  const float* __restrict__ PN,
                                                  ushort_t* __restrict__ h)
{
  int gid = blockIdx.x*256 + threadIdx.x;   // 200000*128 exact
  int i = gid >> 7, d = gid & 127;
  const int* xr = x + i*9;
  float acc = 0.f;
  #pragma unroll
  for (int c = 0; c < 9; c++) acc += PN[(c_noff[c] + xr[c])*HID + d];
  h[gid] = f2bf(acc);
}

// ---------- CSR build (once per launch, reused for all 3 layers) ----------
__global__ __launch_bounds__(256) void hist(const int* __restrict__ ei, int* __restrict__ deg) {
  int e = blockIdx.x*256 + threadIdx.x;
  if (e < NE) atomicAdd(&deg[ei[NE + e]], 1);
}

// block b scans 1024 deg entries -> rowptr[i+1] (local inclusive), bsum[b]=block total
__global__ __launch_bounds__(256) void scan1(const int* __restrict__ deg,
                                             int* __restrict__ rowptr,
                                             int* __restrict__ bsum)
{
  __shared__ int sd[256];
  int b = blockIdx.x, t = threadIdx.x;
  int idx0 = b*1024 + t*4;
  int v[4]; int s = 0;
  #pragma unroll
  for (int j = 0; j < 4; j++) { int i = idx0 + j; v[j] = (i < NN) ? deg[i] : 0; s += v[j]; }
  sd[t] = s; __syncthreads();
  for (int off = 1; off < 256; off <<= 1) {
    int x = (t >= off) ? sd[t - off] : 0; __syncthreads();
    sd[t] += x; __syncthreads();
  }
  int run = (t > 0) ? sd[t-1] : 0;
  #pragma unroll
  for (int j = 0; j < 4; j++) { int i = idx0 + j; run += v[j]; if (i < NN) rowptr[i+1] = run; }
  if (t == 255) bsum[b] = sd[255];
}

__global__ __launch_bounds__(256) void scan2(int* __restrict__ bsum) {
  __shared__ int sd[256];
  int t = threadIdx.x;
  sd[t] = (t < SCAN_NB) ? bsum[t] : 0; __syncthreads();
  for (int off = 1; off < 256; off <<= 1) {
    int x = (t >= off) ? sd[t - off] : 0; __syncthreads();
    sd[t] += x; __syncthreads();
  }
  if (t < SCAN_NB) bsum[t] = sd[t];    // inclusive
}

__global__ __launch_bounds__(256) void scan3(int* __restrict__ rowptr, const int* __restrict__ bsum) {
  int b = blockIdx.x, t = threadIdx.x;
  if (b == 0) { if (t == 0) rowptr[0] = 0; return; }
  int add = bsum[b-1];
  int idx0 = b*1024 + t*4;
  #pragma unroll
  for (int j = 0; j < 4; j++) { int i = idx0 + j; if (i < NN) rowptr[i+1] += add; }
}

// elist[pos] = src | (combo<<18); combo=(a0*6+a1)*2+a2 < 264, src < 2^18
__global__ __launch_bounds__(256) void scatter_e(const int* __restrict__ ei,
                                                 const int* __restrict__ ea,
                                                 int* __restrict__ cursor,
                                                 unsigned* __restrict__ elist)
{
  int e = blockIdx.x*256 + threadIdx.x;
  if (e >= NE) return;
  int src = ei[e], dst = ei[NE + e];
  const int* ar = ea + e*3;
  unsigned combo = (unsigned)((ar[0]*6 + ar[1])*2 + ar[2]);
  int pos = atomicAdd(&cursor[dst], 1);
  elist[pos] = (unsigned)src | (combo << 18);
}

// one wave per node: agg[i] = sum_in relu(h[src] + PE3[combo]), bf16 out, no atomics
__global__ __launch_bounds__(256) void gather_msg(const int* __restrict__ rowptr,
                                                  const unsigned* __restrict__ elist,
                                                  const float* __restrict__ PE3,
                                                  const ushort_t* __restrict__ h,
                                                  unsigned* __restrict__ agg)
{
  int i = blockIdx.x*4 + (threadIdx.x >> 6);
  int lane = threadIdx.x & 63;
  int s = rowptr[i], e = rowptr[i+1];
  const unsigned* h2 = (const unsigned*)h;
  const float2* p2 = (const float2*)PE3;
  float ax = 0.f, ay = 0.f;
  int j = s;
  for (; j + 1 < e; j += 2) {            // 2 edges in flight
    unsigned pk0 = elist[j], pk1 = elist[j+1];
    unsigned hv0 = h2[(size_t)(pk0 & 0x3ffff)*64 + lane];
    unsigned hv1 = h2[(size_t)(pk1 & 0x3ffff)*64 + lane];
    float2 t0 = p2[(size_t)(pk0 >> 18)*64 + lane];
    float2 t1 = p2[(size_t)(pk1 >> 18)*64 + lane];
    ax += fmaxf(bf2f((ushort_t)(hv0 & 0xffff)) + t0.x, 0.f)
        + fmaxf(bf2f((ushort_t)(hv1 & 0xffff)) + t1.x, 0.f);
    ay += fmaxf(bf2f((ushort_t)(hv0 >> 16)) + t0.y, 0.f)
        + fmaxf(bf2f((ushort_t)(hv1 >> 16)) + t1.y, 0.f);
  }
  if (j < e) {
    unsigned pk = elist[j];
    unsigned hv = h2[(size_t)(pk & 0x3ffff)*64 + lane];
    float2 t = p2[(size_t)(pk >> 18)*64 + lane];
    ax += fmaxf(bf2f((ushort_t)(hv & 0xffff)) + t.x, 0.f);
    ay += fmaxf(bf2f((ushort_t)(hv >> 16)) + t.y, 0.f);
  }
  agg[(size_t)i*64 + lane] = (unsigned)f2bf(ax) | ((unsigned)f2bf(ay) << 16);
}

// Fused GINE MLP, IN-PLACE on bf16 h; agg is bf16 now.
__global__ __launch_bounds__(256) void mlp_fused(ushort_t* __restrict__ h,
                                                 const ushort_t* __restrict__ agg,
                                                 const ushort_t* __restrict__ pw,
                                                 const float* __restrict__ b1,
                                                 const float* __restrict__ b2)
{
  __shared__ ushort_t tT[64*136];           // padded stride 136: 2-way (free) bank aliasing
  int tid = threadIdx.x;
  int w = tid >> 6, lane = tid & 63;
  int rbase = blockIdx.x*64 + w*16;
  int arow = rbase + (lane & 15);
  int acol = (lane >> 4) << 3;

  bfrag8 afr[4];
  #pragma unroll
  for (int kt = 0; kt < 4; kt++) {
    int c = kt*32 + acol;
    bfrag8 hfr = *(const bfrag8*)(h   + (size_t)arow*HID + c);
    bfrag8 gfr = *(const bfrag8*)(agg + (size_t)arow*HID + c);
    bfrag8 fr;
    #pragma unroll
    for (int j = 0; j < 8; j++)
      fr[j] = (short)f2bf(bf2f((ushort_t)hfr[j]) + bf2f((ushort_t)gfr[j]));
    afr[kt] = fr;
  }

  int ncol = lane & 15;
  const bfrag8* w1 = (const bfrag8*)pw;
  const bfrag8* w2 = (const bfrag8*)(pw + 16384);

  f32x4 acc[8];
  #pragma unroll
  for (int nt = 0; nt < 8; nt++) {
    float b = b1[nt*16 + ncol];
    acc[nt][0]=b; acc[nt][1]=b; acc[nt][2]=b; acc[nt][3]=b;
  }
  #pragma unroll
  for (int kt = 0; kt < 4; kt++)
    #pragma unroll
    for (int nt = 0; nt < 8; nt++)
      acc[nt] = __builtin_amdgcn_mfma_f32_16x16x32_bf16(afr[kt], w1[(nt*4+kt)*64 + lane], acc[nt], 0, 0, 0);

  #pragma unroll
  for (int nt = 0; nt < 8; nt++) {
    int col = nt*16 + ncol;
    #pragma unroll
    for (int r = 0; r < 4; r++) {
      int row = w*16 + ((lane >> 4) << 2) + r;
      tT[row*136 + col] = f2bf(fmaxf(acc[nt][r], 0.f));
    }
  }
  __syncthreads();

  bfrag8 afr2[4];
  int trow = (w*16 + (lane & 15))*136;
  #pragma unroll
  for (int kt = 0; kt < 4; kt++)
    afr2[kt] = *(const bfrag8*)&tT[trow + kt*32 + acol];

  f32x4 acc2[8];
  #pragma unroll
  for (int nt = 0; nt < 8; nt++) {
    float b = b2[nt*16 + ncol];
    acc2[nt][0]=b; acc2[nt][1]=b; acc2[nt][2]=b; acc2[nt][3]=b;
  }
  #pragma unroll
  for (int kt = 0; kt < 4; kt++)
    #pragma unroll
    for (int nt = 0; nt < 8; nt++)
      acc2[nt] = __builtin_amdgcn_mfma_f32_16x16x32_bf16(afr2[kt], w2[(nt*4+kt)*64 + lane], acc2[nt], 0, 0, 0);

  #pragma unroll
  for (int nt = 0; nt < 8; nt++) {
    int col = nt*16 + ncol;
    #pragma unroll
    for (int r = 0; r < 4; r++) {
      int row = rbase + ((lane >> 4) << 2) + r;
      h[(size_t)row*HID + col] = f2bf(fmaxf(acc2[nt][r], 0.f));
    }
  }
}

__device__ __forceinline__ int lowerb(const int* a, int n, int v) {
  int lo = 0, hi = n;
  while (lo < hi) { int m = (lo + hi) >> 1; if (a[m] < v) lo = m + 1; else hi = m; }
  return lo;
}

__global__ __launch_bounds__(128) void pool(const ushort_t* __restrict__ h,
                                            const int* __restrict__ batch,
                                            float* __restrict__ gf)
{
  int g = blockIdx.x, d = threadIdx.x;
  int s = lowerb(batch, NN, g), e = lowerb(batch, NN, g + 1);
  float acc = 0.f;
  for (int i = s; i < e; i++) acc += bf2f(h[(size_t)i*HID + d]);
  gf[g*HID + d] = acc;
}

__global__ __launch_bounds__(256) void final_proj(const float* __restrict__ gf,
                                                  const float* __restrict__ W,
                                                  const float* __restrict__ b,
                                                  float* __restrict__ out)
{
  __shared__ float gls[16*128];
  __shared__ float part[16][4];
  int tid = threadIdx.x;
  int gbase = blockIdx.x*16;
  for (int idx = tid; idx < 2048; idx += 256) gls[idx] = gf[(size_t)gbase*128 + idx];
  __syncthreads();
  float acc[16];
  #pragma unroll
  for (int g = 0; g < 16; g++) acc[g] = 0.f;
  for (int k = 0; k < 128; k++) {
    float wv = W[(size_t)k*256 + tid];
    #pragma unroll
    for (int g = 0; g < 16; g++) acc[g] += gls[g*128 + k] * wv;
  }
  float bj = b[tid];
  int wid = tid >> 6, lane = tid & 63;
  #pragma unroll
  for (int g = 0; g < 16; g++) {
    acc[g] += bj;
    float s = acc[g]*acc[g];
    #pragma unroll
    for (int off = 32; off > 0; off >>= 1) s += __shfl_xor(s, off, 64);
    if (lane == 0) part[g][wid] = s;
  }
  __syncthreads();
  #pragma unroll
  for (int g = 0; g < 16; g++) {
    float S = part[g][0] + part[g][1] + part[g][2] + part[g][3];
    float rn = 1.f / fmaxf(sqrtf(S), 1e-12f);
    out[(size_t)(gbase + g)*256 + tid] = acc[g]*rn;
  }
}

__global__ __launch_bounds__(256) void ws_diag(float* __restrict__ out, int n, float wsval) {
  int i = blockIdx.x*256 + threadIdx.x;
  if (i < n) out[i] = (i == 0) ? wsval : 0.f;
}

extern "C" void kernel_launch(void* const* d_in, const int* in_sizes, int n_in,
                              void* d_out, int out_size, void* d_ws, size_t ws_size,
                              hipStream_t stream)
{
  const int*   x     = (const int*)d_in[0];
  const int*   ea    = (const int*)d_in[1];
  const int*   ei    = (const int*)d_in[2];
  const int*   batch = (const int*)d_in[3];
  const float* nemb  = (const float*)d_in[4];
  const float* eemb  = (const float*)d_in[5];
  const float* npw   = (const float*)d_in[6];
  const float* npb   = (const float*)d_in[7];
  const float* epw   = (const float*)d_in[8];
  const float* epb   = (const float*)d_in[9];
  const float* w1    = (const float*)d_in[10];
  const float* b1    = (const float*)d_in[11];
  const float* w2    = (const float*)d_in[12];
  const float* b2    = (const float*)d_in[13];
  const float* pjw   = (const float*)d_in[14];
  const float* pjb   = (const float*)d_in[15];
  float* out = (float*)d_out;

  char* ws = (char*)d_ws;
  size_t off = 0;
  auto carve = [&](size_t bytes) -> char* {
    char* p = ws + off;
    off = (off + bytes + 255) & ~(size_t)255;
    return p;
  };
  float*    PN     = (float*)carve((size_t)NODE_TOT*HID*4);
  float*    PE     = (float*)carve((size_t)EDGE_TOT*HID*4);
  float*    PE3    = (float*)carve((size_t)NCOMBO*HID*4);
  ushort_t* PW     = (ushort_t*)carve((size_t)3*2*HID*HID*2);
  ushort_t* h      = (ushort_t*)carve((size_t)NN*HID*2);      // 51.2 MB
  ushort_t* agg    = (ushort_t*)carve((size_t)NN*HID*2);      // 51.2 MB (bf16 now)
  float*    gf     = (float*)carve((size_t)NG*HID*4);
  int*      deg    = (int*)carve((size_t)NN*4);
  int*      rowptr = (int*)carve((size_t)(NN+1)*4);
  int*      cursor = (int*)carve((size_t)NN*4);
  int*      bsum   = (int*)carve((size_t)SCAN_NB*4);
  unsigned* elist  = (unsigned*)carve((size_t)NE*4);

  if (off > ws_size) {
    ws_diag<<<(out_size + 255)/256, 256, 0, stream>>>(out, out_size, (float)ws_size);
    return;
  }

  build_tables<<<NODE_TOT + EDGE_TOT, 128, 0, stream>>>(nemb, eemb, npw, npb, epw, epb, PN, PE);
  build_pe3<<<NCOMBO, 128, 0, stream>>>(PE, PE3);
  pack_w<<<48, 256, 0, stream>>>(w1, w2, PW);
  node_embed<<<(NN*HID)/256, 256, 0, stream>>>(x, PN, h);

  // CSR build (once)
  hipMemsetAsync(deg, 0, (size_t)NN*4, stream);
  hist<<<(NE + 255)/256, 256, 0, stream>>>(ei, deg);
  scan1<<<SCAN_NB, 256, 0, stream>>>(deg, rowptr, bsum);
  scan2<<<1, 256, 0, stream>>>(bsum);
  scan3<<<SCAN_NB, 256, 0, stream>>>(rowptr, bsum);
  hipMemcpyAsync(cursor, rowptr, (size_t)NN*4, hipMemcpyDeviceToDevice, stream);
  scatter_e<<<(NE + 255)/256, 256, 0, stream>>>(ei, ea, cursor, elist);

  for (int l = 0; l < 3; l++) {
    gather_msg<<<NN/4, 256, 0, stream>>>(rowptr, elist, PE3, h, (unsigned*)agg);
    mlp_fused<<<NN/64, 256, 0, stream>>>(h, agg, PW + (size_t)l*2*HID*HID,
                                         b1 + l*HID, b2 + l*HID);
  }
  pool<<<NG, 128, 0, stream>>>(h, batch, gf);
  final_proj<<<NG/16, 256, 0, stream>>>(gf, pjw, pjb, out);
}

// Round 5
// 545.644 us; speedup vs baseline: 2.5770x; 1.0182x over previous
//
#include <hip/hip_runtime.h>
#include <hip/hip_bf16.h>

#define NN 200000
#define NE 400000
#define NG 8000
#define HID 128
#define OUTD 256
#define NODE_TOT 178
#define EDGE_TOT 30
#define NCOMBO 264          // 22*6*2 distinct edge-attr triples
#define SCAN_NB 196         // ceil(NN/1024)

typedef __attribute__((ext_vector_type(8))) short bfrag8;
typedef __attribute__((ext_vector_type(4))) float f32x4;
typedef unsigned short ushort_t;

__constant__ int c_noff[10] = {0,119,128,139,151,161,166,174,176,178};

__device__ __forceinline__ ushort_t f2bf(float f) {
  union { float f; unsigned u; } x; x.f = f;
  unsigned r = x.u + 0x7fffu + ((x.u >> 16) & 1u);
  return (ushort_t)(r >> 16);
}
__device__ __forceinline__ float bf2f(ushort_t u) {
  union { unsigned u; float f; } x; x.u = ((unsigned)u) << 16;
  return x.f;
}

// Projected embedding tables: PN[r][d] = emb[r] . W_c[:,d] (+bias folded into col 0)
__global__ __launch_bounds__(128) void build_tables(
    const float* __restrict__ node_emb, const float* __restrict__ edge_emb,
    const float* __restrict__ npw, const float* __restrict__ npb,
    const float* __restrict__ epw, const float* __restrict__ epb,
    float* __restrict__ PN, float* __restrict__ PE)
{
  int r = blockIdx.x, d = threadIdx.x;
  if (r < NODE_TOT) {
    int c = 0;
    while (r >= c_noff[c+1]) c++;
    float acc = (c == 0) ? npb[d] : 0.f;
    const float* er = node_emb + r*HID;
    const float* wb = npw + (size_t)(c*HID)*HID + d;
    for (int k = 0; k < HID; k++) acc += er[k] * wb[(size_t)k*HID];
    PN[r*HID + d] = acc;
  } else {
    int re = r - NODE_TOT;
    int c = (re >= 28) ? 2 : (re >= 22 ? 1 : 0);
    float acc = (c == 0) ? epb[d] : 0.f;
    const float* er = edge_emb + re*HID;
    const float* wb = epw + (size_t)(c*HID)*HID + d;
    for (int k = 0; k < HID; k++) acc += er[k] * wb[(size_t)k*HID];
    PE[re*HID + d] = acc;
  }
}

// PE3[(a0*6+a1)*2+a2] = PE[a0] + PE[22+a1] + PE[28+a2]
__global__ __launch_bounds__(128) void build_pe3(const float* __restrict__ PE,
                                                 float* __restrict__ PE3)
{
  int c = blockIdx.x, d = threadIdx.x;
  int a2 = c & 1, a1 = (c >> 1) % 6, a0 = (c >> 1) / 6;
  PE3[c*HID + d] = PE[a0*HID + d] + PE[(22+a1)*HID + d] + PE[(28+a2)*HID + d];
}

// Pack mlp_w1/mlp_w2 into bf16 MFMA B-fragment order
__global__ __launch_bounds__(256) void pack_w(const float* __restrict__ w1,
                                              const float* __restrict__ w2,
                                              ushort_t* __restrict__ pw)
{
  int t = blockIdx.x*256 + threadIdx.x;     // 12288 total
  int lane = t & 63, tile = (t >> 6) & 31, pair = t >> 11;
  int layer = pair >> 1, isw2 = pair & 1;
  int nt = tile >> 2, kt = tile & 3;
  int n  = nt*16 + (lane & 15);
  int k0 = kt*32 + ((lane >> 4) << 3);
  const float* src = (isw2 ? w2 : w1) + (size_t)layer*HID*HID;
  ushort_t* dst = pw + (size_t)t*8;
  #pragma unroll
  for (int j = 0; j < 8; j++) dst[j] = f2bf(src[(size_t)(k0+j)*HID + n]);
}

// 4 dims/thread: f32x4 table loads, 4 ILP chains, 8B packed bf16 store
__global__ __launch_bounds__(256) void node_embed(const int* __restrict__ x,
                                                  const float* __restrict__ PN,
                                                  ushort_t* __restrict__ h)
{
  int gid = blockIdx.x*256 + threadIdx.x;   // NN*32 total, exact
  int i = gid >> 5, d0 = (gid & 31) << 2;
  const int* xr = x + i*9;
  f32x4 acc = {0.f, 0.f, 0.f, 0.f};
  #pragma unroll
  for (int c = 0; c < 9; c++)
    acc += *(const f32x4*)&PN[(c_noff[c] + xr[c])*HID + d0];
  uint2 pk;
  pk.x = (unsigned)f2bf(acc[0]) | ((unsigned)f2bf(acc[1]) << 16);
  pk.y = (unsigned)f2bf(acc[2]) | ((unsigned)f2bf(acc[3]) << 16);
  *(uint2*)&h[(size_t)i*HID + d0] = pk;
}

// ---------- CSR build (once per launch, reused for all 3 layers) ----------
__global__ __launch_bounds__(256) void hist(const int* __restrict__ ei, int* __restrict__ deg) {
  int e = blockIdx.x*256 + threadIdx.x;
  if (e < NE) atomicAdd(&deg[ei[NE + e]], 1);
}

__global__ __launch_bounds__(256) void scan1(const int* __restrict__ deg,
                                             int* __restrict__ rowptr,
                                             int* __restrict__ bsum)
{
  __shared__ int sd[256];
  int b = blockIdx.x, t = threadIdx.x;
  int idx0 = b*1024 + t*4;
  int v[4]; int s = 0;
  #pragma unroll
  for (int j = 0; j < 4; j++) { int i = idx0 + j; v[j] = (i < NN) ? deg[i] : 0; s += v[j]; }
  sd[t] = s; __syncthreads();
  for (int off = 1; off < 256; off <<= 1) {
    int x = (t >= off) ? sd[t - off] : 0; __syncthreads();
    sd[t] += x; __syncthreads();
  }
  int run = (t > 0) ? sd[t-1] : 0;
  #pragma unroll
  for (int j = 0; j < 4; j++) { int i = idx0 + j; run += v[j]; if (i < NN) rowptr[i+1] = run; }
  if (t == 255) bsum[b] = sd[255];
}

__global__ __launch_bounds__(256) void scan2(int* __restrict__ bsum) {
  __shared__ int sd[256];
  int t = threadIdx.x;
  sd[t] = (t < SCAN_NB) ? bsum[t] : 0; __syncthreads();
  for (int off = 1; off < 256; off <<= 1) {
    int x = (t >= off) ? sd[t - off] : 0; __syncthreads();
    sd[t] += x; __syncthreads();
  }
  if (t < SCAN_NB) bsum[t] = sd[t];    // inclusive
}

__global__ __launch_bounds__(256) void scan3(int* __restrict__ rowptr, const int* __restrict__ bsum) {
  int b = blockIdx.x, t = threadIdx.x;
  if (b == 0) { if (t == 0) rowptr[0] = 0; return; }
  int add = bsum[b-1];
  int idx0 = b*1024 + t*4;
  #pragma unroll
  for (int j = 0; j < 4; j++) { int i = idx0 + j; if (i < NN) rowptr[i+1] += add; }
}

// elist[pos] = src | (combo<<18); combo=(a0*6+a1)*2+a2 < 264, src < 2^18
__global__ __launch_bounds__(256) void scatter_e(const int* __restrict__ ei,
                                                 const int* __restrict__ ea,
                                                 int* __restrict__ cursor,
                                                 unsigned* __restrict__ elist)
{
  int e = blockIdx.x*256 + threadIdx.x;
  if (e >= NE) return;
  int src = ei[e], dst = ei[NE + e];
  const int* ar = ea + e*3;
  unsigned combo = (unsigned)((ar[0]*6 + ar[1])*2 + ar[2]);
  int pos = atomicAdd(&cursor[dst], 1);
  elist[pos] = (unsigned)src | (combo << 18);
}

// one wave per node: agg[i] = sum_in relu(h[src] + PE3[combo]), bf16 out, no atomics
__global__ __launch_bounds__(256) void gather_msg(const int* __restrict__ rowptr,
                                                  const unsigned* __restrict__ elist,
                                                  const float* __restrict__ PE3,
                                                  const ushort_t* __restrict__ h,
                                                  unsigned* __restrict__ agg)
{
  int i = blockIdx.x*4 + (threadIdx.x >> 6);
  int lane = threadIdx.x & 63;
  int s = rowptr[i], e = rowptr[i+1];
  const unsigned* h2 = (const unsigned*)h;
  const float2* p2 = (const float2*)PE3;
  float ax = 0.f, ay = 0.f;
  int j = s;
  for (; j + 1 < e; j += 2) {            // 2 edges in flight
    unsigned pk0 = elist[j], pk1 = elist[j+1];
    unsigned hv0 = h2[(size_t)(pk0 & 0x3ffff)*64 + lane];
    unsigned hv1 = h2[(size_t)(pk1 & 0x3ffff)*64 + lane];
    float2 t0 = p2[(size_t)(pk0 >> 18)*64 + lane];
    float2 t1 = p2[(size_t)(pk1 >> 18)*64 + lane];
    ax += fmaxf(bf2f((ushort_t)(hv0 & 0xffff)) + t0.x, 0.f)
        + fmaxf(bf2f((ushort_t)(hv1 & 0xffff)) + t1.x, 0.f);
    ay += fmaxf(bf2f((ushort_t)(hv0 >> 16)) + t0.y, 0.f)
        + fmaxf(bf2f((ushort_t)(hv1 >> 16)) + t1.y, 0.f);
  }
  if (j < e) {
    unsigned pk = elist[j];
    unsigned hv = h2[(size_t)(pk & 0x3ffff)*64 + lane];
    float2 t = p2[(size_t)(pk >> 18)*64 + lane];
    ax += fmaxf(bf2f((ushort_t)(hv & 0xffff)) + t.x, 0.f);
    ay += fmaxf(bf2f((ushort_t)(hv >> 16)) + t.y, 0.f);
  }
  agg[(size_t)i*64 + lane] = (unsigned)f2bf(ax) | ((unsigned)f2bf(ay) << 16);
}

// Fused GINE MLP, IN-PLACE on bf16 h; M_rep=2: wave=32 rows, block=128 rows.
// Each weight fragment load serves 2 row-tiles -> L2 weight traffic halved.
__global__ __launch_bounds__(256, 2) void mlp_fused(ushort_t* __restrict__ h,
                                                    const ushort_t* __restrict__ agg,
                                                    const ushort_t* __restrict__ pw,
                                                    const float* __restrict__ b1,
                                                    const float* __restrict__ b2)
{
  __shared__ ushort_t tT[128*136];          // padded stride 136: 2-way (free) aliasing
  int tid = threadIdx.x;
  int w = tid >> 6, lane = tid & 63;
  int rblk = blockIdx.x*128;                // block rows [rblk, rblk+128)
  int wrow = w*32;                          // wave's 32 rows within block
  int acol = (lane >> 4) << 3;
  int ncol = lane & 15;

  // A fragments of z = h + agg for 2 row-tiles
  bfrag8 afr[2][4];
  #pragma unroll
  for (int m = 0; m < 2; m++) {
    int arow = rblk + wrow + m*16 + (lane & 15);
    bool ok = arow < NN;
    #pragma unroll
    for (int kt = 0; kt < 4; kt++) {
      bfrag8 fr = (bfrag8){0,0,0,0,0,0,0,0};
      if (ok) {
        int c = kt*32 + acol;
        bfrag8 hfr = *(const bfrag8*)(h   + (size_t)arow*HID + c);
        bfrag8 gfr = *(const bfrag8*)(agg + (size_t)arow*HID + c);
        #pragma unroll
        for (int j = 0; j < 8; j++)
          fr[j] = (short)f2bf(bf2f((ushort_t)hfr[j]) + bf2f((ushort_t)gfr[j]));
      }
      afr[m][kt] = fr;
    }
  }

  const bfrag8* w1 = (const bfrag8*)pw;
  const bfrag8* w2 = (const bfrag8*)(pw + 16384);

  f32x4 acc[8][2];
  #pragma unroll
  for (int nt = 0; nt < 8; nt++) {
    float b = b1[nt*16 + ncol];
    #pragma unroll
    for (int m = 0; m < 2; m++) { acc[nt][m][0]=b; acc[nt][m][1]=b; acc[nt][m][2]=b; acc[nt][m][3]=b; }
  }
  #pragma unroll
  for (int kt = 0; kt < 4; kt++)
    #pragma unroll
    for (int nt = 0; nt < 8; nt++) {
      bfrag8 wf = w1[(nt*4+kt)*64 + lane];
      #pragma unroll
      for (int m = 0; m < 2; m++)
        acc[nt][m] = __builtin_amdgcn_mfma_f32_16x16x32_bf16(afr[m][kt], wf, acc[nt][m], 0, 0, 0);
    }

  // t = relu(.) -> LDS
  #pragma unroll
  for (int nt = 0; nt < 8; nt++) {
    int col = nt*16 + ncol;
    #pragma unroll
    for (int m = 0; m < 2; m++)
      #pragma unroll
      for (int r = 0; r < 4; r++) {
        int row = wrow + m*16 + ((lane >> 4) << 2) + r;
        tT[row*136 + col] = f2bf(fmaxf(acc[nt][m][r], 0.f));
      }
  }
  __syncthreads();

  bfrag8 afr2[2][4];
  #pragma unroll
  for (int m = 0; m < 2; m++) {
    int trow = (wrow + m*16 + (lane & 15))*136;
    #pragma unroll
    for (int kt = 0; kt < 4; kt++)
      afr2[m][kt] = *(const bfrag8*)&tT[trow + kt*32 + acol];
  }

  f32x4 acc2[8][2];
  #pragma unroll
  for (int nt = 0; nt < 8; nt++) {
    float b = b2[nt*16 + ncol];
    #pragma unroll
    for (int m = 0; m < 2; m++) { acc2[nt][m][0]=b; acc2[nt][m][1]=b; acc2[nt][m][2]=b; acc2[nt][m][3]=b; }
  }
  #pragma unroll
  for (int kt = 0; kt < 4; kt++)
    #pragma unroll
    for (int nt = 0; nt < 8; nt++) {
      bfrag8 wf = w2[(nt*4+kt)*64 + lane];
      #pragma unroll
      for (int m = 0; m < 2; m++)
        acc2[nt][m] = __builtin_amdgcn_mfma_f32_16x16x32_bf16(afr2[m][kt], wf, acc2[nt][m], 0, 0, 0);
    }

  #pragma unroll
  for (int nt = 0; nt < 8; nt++) {
    int col = nt*16 + ncol;
    #pragma unroll
    for (int m = 0; m < 2; m++)
      #pragma unroll
      for (int r = 0; r < 4; r++) {
        int row = rblk + wrow + m*16 + ((lane >> 4) << 2) + r;
        if (row < NN) h[(size_t)row*HID + col] = f2bf(fmaxf(acc2[nt][m][r], 0.f));
      }
  }
}

__device__ __forceinline__ int lowerb(const int* a, int n, int v) {
  int lo = 0, hi = n;
  while (lo < hi) { int m = (lo + hi) >> 1; if (a[m] < v) lo = m + 1; else hi = m; }
  return lo;
}

__global__ __launch_bounds__(128) void pool(const ushort_t* __restrict__ h,
                                            const int* __restrict__ batch,
                                            float* __restrict__ gf)
{
  int g = blockIdx.x, d = threadIdx.x;
  int s = lowerb(batch, NN, g), e = lowerb(batch, NN, g + 1);
  float acc = 0.f;
  for (int i = s; i < e; i++) acc += bf2f(h[(size_t)i*HID + d]);
  gf[g*HID + d] = acc;
}

__global__ __launch_bounds__(256) void final_proj(const float* __restrict__ gf,
                                                  const float* __restrict__ W,
                                                  const float* __restrict__ b,
                                                  float* __restrict__ out)
{
  __shared__ float gls[16*128];
  __shared__ float part[16][4];
  int tid = threadIdx.x;
  int gbase = blockIdx.x*16;
  for (int idx = tid; idx < 2048; idx += 256) gls[idx] = gf[(size_t)gbase*128 + idx];
  __syncthreads();
  float acc[16];
  #pragma unroll
  for (int g = 0; g < 16; g++) acc[g] = 0.f;
  for (int k = 0; k < 128; k++) {
    float wv = W[(size_t)k*256 + tid];
    #pragma unroll
    for (int g = 0; g < 16; g++) acc[g] += gls[g*128 + k] * wv;
  }
  float bj = b[tid];
  int wid = tid >> 6, lane = tid & 63;
  #pragma unroll
  for (int g = 0; g < 16; g++) {
    acc[g] += bj;
    float s = acc[g]*acc[g];
    #pragma unroll
    for (int off = 32; off > 0; off >>= 1) s += __shfl_xor(s, off, 64);
    if (lane == 0) part[g][wid] = s;
  }
  __syncthreads();
  #pragma unroll
  for (int g = 0; g < 16; g++) {
    float S = part[g][0] + part[g][1] + part[g][2] + part[g][3];
    float rn = 1.f / fmaxf(sqrtf(S), 1e-12f);
    out[(size_t)(gbase + g)*256 + tid] = acc[g]*rn;
  }
}

__global__ __launch_bounds__(256) void ws_diag(float* __restrict__ out, int n, float wsval) {
  int i = blockIdx.x*256 + threadIdx.x;
  if (i < n) out[i] = (i == 0) ? wsval : 0.f;
}

extern "C" void kernel_launch(void* const* d_in, const int* in_sizes, int n_in,
                              void* d_out, int out_size, void* d_ws, size_t ws_size,
                              hipStream_t stream)
{
  const int*   x     = (const int*)d_in[0];
  const int*   ea    = (const int*)d_in[1];
  const int*   ei    = (const int*)d_in[2];
  const int*   batch = (const int*)d_in[3];
  const float* nemb  = (const float*)d_in[4];
  const float* eemb  = (const float*)d_in[5];
  const float* npw   = (const float*)d_in[6];
  const float* npb   = (const float*)d_in[7];
  const float* epw   = (const float*)d_in[8];
  const float* epb   = (const float*)d_in[9];
  const float* w1    = (const float*)d_in[10];
  const float* b1    = (const float*)d_in[11];
  const float* w2    = (const float*)d_in[12];
  const float* b2    = (const float*)d_in[13];
  const float* pjw   = (const float*)d_in[14];
  const float* pjb   = (const float*)d_in[15];
  float* out = (float*)d_out;

  char* ws = (char*)d_ws;
  size_t off = 0;
  auto carve = [&](size_t bytes) -> char* {
    char* p = ws + off;
    off = (off + bytes + 255) & ~(size_t)255;
    return p;
  };
  float*    PN     = (float*)carve((size_t)NODE_TOT*HID*4);
  float*    PE     = (float*)carve((size_t)EDGE_TOT*HID*4);
  float*    PE3    = (float*)carve((size_t)NCOMBO*HID*4);
  ushort_t* PW     = (ushort_t*)carve((size_t)3*2*HID*HID*2);
  ushort_t* h      = (ushort_t*)carve((size_t)NN*HID*2);      // 51.2 MB
  ushort_t* agg    = (ushort_t*)carve((size_t)NN*HID*2);      // 51.2 MB
  float*    gf     = (float*)carve((size_t)NG*HID*4);
  int*      deg    = (int*)carve((size_t)NN*4);
  int*      rowptr = (int*)carve((size_t)(NN+1)*4);
  int*      cursor = (int*)carve((size_t)NN*4);
  int*      bsum   = (int*)carve((size_t)SCAN_NB*4);
  unsigned* elist  = (unsigned*)carve((size_t)NE*4);

  if (off > ws_size) {
    ws_diag<<<(out_size + 255)/256, 256, 0, stream>>>(out, out_size, (float)ws_size);
    return;
  }

  build_tables<<<NODE_TOT + EDGE_TOT, 128, 0, stream>>>(nemb, eemb, npw, npb, epw, epb, PN, PE);
  build_pe3<<<NCOMBO, 128, 0, stream>>>(PE, PE3);
  pack_w<<<48, 256, 0, stream>>>(w1, w2, PW);
  node_embed<<<(NN*32)/256, 256, 0, stream>>>(x, PN, h);

  // CSR build (once)
  hipMemsetAsync(deg, 0, (size_t)NN*4, stream);
  hist<<<(NE + 255)/256, 256, 0, stream>>>(ei, deg);
  scan1<<<SCAN_NB, 256, 0, stream>>>(deg, rowptr, bsum);
  scan2<<<1, 256, 0, stream>>>(bsum);
  scan3<<<SCAN_NB, 256, 0, stream>>>(rowptr, bsum);
  hipMemcpyAsync(cursor, rowptr, (size_t)NN*4, hipMemcpyDeviceToDevice, stream);
  scatter_e<<<(NE + 255)/256, 256, 0, stream>>>(ei, ea, cursor, elist);

  for (int l = 0; l < 3; l++) {
    gather_msg<<<NN/4, 256, 0, stream>>>(rowptr, elist, PE3, h, (unsigned*)agg);
    mlp_fused<<<(NN + 127)/128, 256, 0, stream>>>(h, agg, PW + (size_t)l*2*HID*HID,
                                                  b1 + l*HID, b2 + l*HID);
  }
  pool<<<NG, 128, 0, stream>>>(h, batch, gf);
  final_proj<<<NG/16, 256, 0, stream>>>(gf, pjw, pjb, out);
}